// Round 1
// baseline (75313.062 us; speedup 1.0000x reference)
//
#include <hip/hip_runtime.h>

#define N_NODES 100000
#define N_EDGES 800000
#define D 128
#define NLAYERS 3
#define NREL 3

__global__ void wsum_kernel(const float* __restrict__ W_r, const float* __restrict__ b_l,
                            float* __restrict__ wsum, float* __restrict__ bsum) {
    int idx = blockIdx.x * 256 + threadIdx.x;
    if (idx < NLAYERS * D * D) {
        int i = idx / (D * D);
        int rest = idx % (D * D);
        const float* base = W_r + (size_t)i * NREL * D * D;
        wsum[idx] = base[rest] + base[D * D + rest] + base[2 * D * D + rest];
    }
    if (idx < NLAYERS * D) {
        int i = idx / D;
        int o = idx % D;
        const float* bb = b_l + (size_t)i * NREL * D;
        bsum[idx] = bb[o] + bb[D + o] + bb[2 * D + o];
    }
}

__global__ void count_kernel(const int* __restrict__ ei, int* __restrict__ cnt) {
    int e = blockIdx.x * 256 + threadIdx.x;
    if (e < N_EDGES) {
        atomicAdd(&cnt[ei[N_EDGES + e]], 1);
    }
}

__global__ void scan_kernel(const int* __restrict__ cnt, int* __restrict__ ptr) {
    int r = blockIdx.x;
    const int* c = cnt + (size_t)r * N_NODES;
    int* p = ptr + (size_t)r * (N_NODES + 1);
    __shared__ int sums[1024];
    int tid = threadIdx.x;
    const int CH = (N_NODES + 1023) / 1024;  // 98
    int base = tid * CH;
    int s = 0;
    for (int j = 0; j < CH; j++) {
        int idx = base + j;
        if (idx < N_NODES) s += c[idx];
    }
    sums[tid] = s;
    __syncthreads();
    for (int off = 1; off < 1024; off <<= 1) {
        int v = sums[tid];
        int add = (tid >= off) ? sums[tid - off] : 0;
        __syncthreads();
        sums[tid] = v + add;
        __syncthreads();
    }
    int run = (tid == 0) ? 0 : sums[tid - 1];
    for (int j = 0; j < CH; j++) {
        int idx = base + j;
        if (idx < N_NODES) {
            p[idx] = run;
            run += c[idx];
        }
    }
    if (tid == 1023) p[N_NODES] = sums[1023];
}

__global__ void fill_kernel(const int* __restrict__ ei, const int* __restrict__ em,
                            const int* __restrict__ ptr, int* __restrict__ fill,
                            int* __restrict__ packed) {
    int e = blockIdx.x * 256 + threadIdx.x;
    if (e < N_EDGES) {
        int dst = ei[N_EDGES + e];
        int src = ei[e];
        int m = em[e];
        int pos = ptr[dst] + atomicAdd(&fill[dst], 1);
        packed[pos] = src | (m << 17);
    }
}

// one block per dst node; 128 threads = feature dims
__global__ void agg_kernel(const float* __restrict__ h, const int* __restrict__ ptr,
                           const int* __restrict__ packed, float* __restrict__ mean, int layer) {
    int n = blockIdx.x;
    int d = threadIdx.x;
    int beg = ptr[n], end = ptr[n + 1];
    float acc = 0.f;
    int c = 0;
    for (int e = beg; e < end; e++) {
        int pk = packed[e];
        if ((pk >> 17) <= layer) {
            acc += h[(size_t)(pk & 0x1FFFF) * D + d];
            c++;
        }
    }
    mean[(size_t)n * D + d] = acc / fmaxf((float)c, 1.0f);
}

// fused 4-pair GEMM: out[n,:] = relu_mask( sum_p A_p[n,:] @ W_p^T + bias )
// 32 rows x 128 cols per block, 256 threads, 4x4 register tile per thread
__global__ __launch_bounds__(256) void gemm_fused(
    const float* __restrict__ A0, const float* __restrict__ A1,
    const float* __restrict__ A2, const float* __restrict__ A3,
    const float* __restrict__ W0, const float* __restrict__ W1,
    const float* __restrict__ W2, const float* __restrict__ W3,
    const float* __restrict__ bias, const int* __restrict__ node_mask,
    int layer, float* __restrict__ out) {
    __shared__ float Ws[128][68];  // 68 pad: breaks stride-128 bank conflict, keeps 16B align
    __shared__ float As[32][64];
    const float* Aps[4] = {A0, A1, A2, A3};
    const float* Wps[4] = {W0, W1, W2, W3};
    int tid = threadIdx.x;
    int row0 = blockIdx.x * 32;
    int tr = tid >> 5;  // 0..7
    int tc = tid & 31;  // 0..31
    float acc[4][4];
#pragma unroll
    for (int a = 0; a < 4; a++)
#pragma unroll
        for (int b = 0; b < 4; b++) acc[a][b] = 0.f;

#pragma unroll
    for (int p = 0; p < 4; p++) {
        const float* Ap = Aps[p];
        const float* Wp = Wps[p];
#pragma unroll
        for (int kc = 0; kc < 2; kc++) {
            __syncthreads();
            // load W chunk 128x64 (2048 float4, 8 per thread)
#pragma unroll
            for (int i = 0; i < 8; i++) {
                int s = tid + i * 256;
                int o = s >> 4, k4 = s & 15;
                float4 v = *reinterpret_cast<const float4*>(Wp + (size_t)o * 128 + kc * 64 + k4 * 4);
                *reinterpret_cast<float4*>(&Ws[o][k4 * 4]) = v;
            }
            // load A tile 32x64 (512 float4, 2 per thread)
#pragma unroll
            for (int i = 0; i < 2; i++) {
                int s = tid + i * 256;
                int rr = s >> 4, k4 = s & 15;
                float4 v = *reinterpret_cast<const float4*>(Ap + (size_t)(row0 + rr) * 128 + kc * 64 + k4 * 4);
                *reinterpret_cast<float4*>(&As[rr][k4 * 4]) = v;
            }
            __syncthreads();
#pragma unroll
            for (int k4 = 0; k4 < 16; k4++) {
                float4 a4[4], w4[4];
#pragma unroll
                for (int rr = 0; rr < 4; rr++)
                    a4[rr] = *reinterpret_cast<const float4*>(&As[tr + 8 * rr][k4 * 4]);
#pragma unroll
                for (int cc = 0; cc < 4; cc++)
                    w4[cc] = *reinterpret_cast<const float4*>(&Ws[tc + 32 * cc][k4 * 4]);
#pragma unroll
                for (int rr = 0; rr < 4; rr++)
#pragma unroll
                    for (int cc = 0; cc < 4; cc++) {
                        acc[rr][cc] += a4[rr].x * w4[cc].x;
                        acc[rr][cc] += a4[rr].y * w4[cc].y;
                        acc[rr][cc] += a4[rr].z * w4[cc].z;
                        acc[rr][cc] += a4[rr].w * w4[cc].w;
                    }
            }
        }
    }
    // epilogue: bias + node-mask + relu, write (in-place on h is safe: block-private rows)
#pragma unroll
    for (int rr = 0; rr < 4; rr++) {
        int n = row0 + tr + 8 * rr;
        bool valid = node_mask[n] <= layer;
#pragma unroll
        for (int cc = 0; cc < 4; cc++) {
            int c = tc + 32 * cc;
            float v = acc[rr][cc] + bias[c];
            out[(size_t)n * 128 + c] = valid ? fmaxf(v, 0.f) : 0.f;
        }
    }
}

extern "C" void kernel_launch(void* const* d_in, const int* in_sizes, int n_in,
                              void* d_out, int out_size, void* d_ws, size_t ws_size,
                              hipStream_t stream) {
    const float* x = (const float*)d_in[0];
    const int* eis[3] = {(const int*)d_in[1], (const int*)d_in[2], (const int*)d_in[3]};
    const int* node_mask = (const int*)d_in[4];
    const int* ems[3] = {(const int*)d_in[5], (const int*)d_in[6], (const int*)d_in[7]};
    const float* W_l = (const float*)d_in[8];
    const float* b_l = (const float*)d_in[9];
    const float* W_r = (const float*)d_in[10];

    // workspace layout
    float* h = (float*)d_ws;                                 // N*D
    float* mean = h + (size_t)N_NODES * D;                   // 3*N*D
    int* cnt = (int*)(mean + (size_t)3 * N_NODES * D);       // 3*N
    int* ptr = cnt + 3 * N_NODES;                            // 3*(N+1)
    int* fill = ptr + 3 * (N_NODES + 1);                     // 3*N
    int* packed = fill + 3 * N_NODES;                        // 3*E
    float* wsum = (float*)(packed + (size_t)3 * N_EDGES);    // 3*D*D
    float* bsum = wsum + 3 * D * D;                          // 3*D

    // zero cnt + ptr + fill in one contiguous memset
    hipMemsetAsync(cnt, 0, (size_t)(3 * N_NODES + 3 * (N_NODES + 1) + 3 * N_NODES) * sizeof(int), stream);

    wsum_kernel<<<(3 * D * D + 255) / 256, 256, 0, stream>>>(W_r, b_l, wsum, bsum);

    for (int t = 0; t < 3; t++)
        count_kernel<<<(N_EDGES + 255) / 256, 256, 0, stream>>>(eis[t], cnt + t * N_NODES);
    scan_kernel<<<3, 1024, 0, stream>>>(cnt, ptr);
    for (int t = 0; t < 3; t++)
        fill_kernel<<<(N_EDGES + 255) / 256, 256, 0, stream>>>(
            eis[t], ems[t], ptr + t * (N_NODES + 1), fill + t * N_NODES, packed + (size_t)t * N_EDGES);

    for (int i = 0; i < 3; i++) {
        int layer = NLAYERS - i;
        const float* hin = (i == 0) ? x : h;
        for (int t = 0; t < 3; t++)
            agg_kernel<<<N_NODES, 128, 0, stream>>>(
                hin, ptr + t * (N_NODES + 1), packed + (size_t)t * N_EDGES,
                mean + (size_t)t * N_NODES * D, layer);
        float* hout = (i == 2) ? (float*)d_out : h;
        gemm_fused<<<N_NODES / 32, 256, 0, stream>>>(
            mean, mean + (size_t)N_NODES * D, mean + (size_t)2 * N_NODES * D, hin,
            W_l + (size_t)(i * 3 + 0) * D * D, W_l + (size_t)(i * 3 + 1) * D * D,
            W_l + (size_t)(i * 3 + 2) * D * D, wsum + (size_t)i * D * D,
            bsum + (size_t)i * D, node_mask, layer, hout);
    }
}

// Round 4
// 1835.928 us; speedup vs baseline: 41.0218x; 41.0218x over previous
//
#include <hip/hip_runtime.h>

#define N_NODES 100000
#define N_EDGES 800000
#define D 128

typedef __attribute__((ext_vector_type(8))) short bf16x8;
typedef __attribute__((ext_vector_type(4))) float f32x4;

#define MFMA_BF16(a, b, c) __builtin_amdgcn_mfma_f32_16x16x32_bf16((a), (b), (c), 0, 0, 0)

__device__ __forceinline__ uint f2bf_rne(float f) {
    uint u = __float_as_uint(f);
    return (u + 0x7FFFu + ((u >> 16) & 1u)) >> 16;
}
__device__ __forceinline__ float bf2f(uint b) { return __uint_as_float(b << 16); }

__device__ __forceinline__ void splitf(float f, uint& hi, uint& lo) {
    hi = f2bf_rne(f);
    float r = f - bf2f(hi);
    lo = f2bf_rne(r);
}

// ---- x f32 -> (hi, lo) bf16 planes; one float4 per thread
__global__ void conv_x(const float* __restrict__ x, ushort* __restrict__ hhi,
                       ushort* __restrict__ hlo) {
    int idx = blockIdx.x * 256 + threadIdx.x;
    float4 v = reinterpret_cast<const float4*>(x)[idx];
    uint h0, l0, h1, l1, h2, l2, h3, l3;
    splitf(v.x, h0, l0);
    splitf(v.y, h1, l1);
    splitf(v.z, h2, l2);
    splitf(v.w, h3, l3);
    ushort4 hv = {(ushort)h0, (ushort)h1, (ushort)h2, (ushort)h3};
    ushort4 lv = {(ushort)l0, (ushort)l1, (ushort)l2, (ushort)l3};
    reinterpret_cast<ushort4*>(hhi)[idx] = hv;
    reinterpret_cast<ushort4*>(hlo)[idx] = lv;
}

// ---- weight prep: w{hi,lo}[i][slot][o][k]; slot 0..2 = W_l[i][t], slot 3 = sum_t W_r[i][t]
__global__ void prep_w(const float* __restrict__ W_l, const float* __restrict__ W_r,
                       const float* __restrict__ b_l, ushort* __restrict__ whi,
                       ushort* __restrict__ wlo, float* __restrict__ bsum) {
    int idx = blockIdx.x * 256 + threadIdx.x;
    if (idx < 3 * 4 * 16384) {
        int i = idx / (4 * 16384);
        int rem = idx % (4 * 16384);
        int slot = rem / 16384;
        int ok = rem % 16384;
        float v;
        if (slot < 3) {
            v = W_l[(size_t)(i * 3 + slot) * 16384 + ok];
        } else {
            const float* base = W_r + (size_t)i * 3 * 16384;
            v = base[ok] + base[16384 + ok] + base[2 * 16384 + ok];
        }
        uint hi, lo;
        splitf(v, hi, lo);
        whi[idx] = (ushort)hi;
        wlo[idx] = (ushort)lo;
    }
    if (idx < 3 * 128) {
        int i = idx / 128, o = idx % 128;
        const float* bb = b_l + (size_t)i * 3 * 128;
        bsum[idx] = bb[o] + bb[128 + o] + bb[256 + o];
    }
}

// ---- CSR build (per relation)
__global__ void count_kernel(const int* __restrict__ ei, int* __restrict__ cnt) {
    int e = blockIdx.x * 256 + threadIdx.x;
    if (e < N_EDGES) atomicAdd(&cnt[ei[N_EDGES + e]], 1);
}

__global__ void scan_kernel(const int* __restrict__ cnt, int* __restrict__ ptr) {
    int r = blockIdx.x;
    const int* c = cnt + (size_t)r * N_NODES;
    int* p = ptr + (size_t)r * (N_NODES + 1);
    __shared__ int sums[1024];
    int tid = threadIdx.x;
    const int CH = (N_NODES + 1023) / 1024;
    int base = tid * CH;
    int s = 0;
    for (int j = 0; j < CH; j++) {
        int idx = base + j;
        if (idx < N_NODES) s += c[idx];
    }
    sums[tid] = s;
    __syncthreads();
    for (int off = 1; off < 1024; off <<= 1) {
        int v = sums[tid];
        int add = (tid >= off) ? sums[tid - off] : 0;
        __syncthreads();
        sums[tid] = v + add;
        __syncthreads();
    }
    int run = (tid == 0) ? 0 : sums[tid - 1];
    for (int j = 0; j < CH; j++) {
        int idx = base + j;
        if (idx < N_NODES) {
            p[idx] = run;
            run += c[idx];
        }
    }
    if (tid == 1023) p[N_NODES] = sums[1023];
}

__global__ void fill_kernel(const int* __restrict__ ei, const int* __restrict__ em,
                            const int* __restrict__ ptr, int* __restrict__ fill,
                            int* __restrict__ packed) {
    int e = blockIdx.x * 256 + threadIdx.x;
    if (e < N_EDGES) {
        int dst = ei[N_EDGES + e];
        int src = ei[e];
        int m = em[e];
        int pos = ptr[dst] + atomicAdd(&fill[dst], 1);
        packed[pos] = src | (m << 17);
    }
}

// ---- aggregation: one wave per dst node; lane owns 2 feature cols; f32 accumulate
__global__ __launch_bounds__(256) void agg_kernel(
    const ushort* __restrict__ hhi, const ushort* __restrict__ hlo,
    const int* __restrict__ ptr, const int* __restrict__ packed,
    ushort* __restrict__ mhi, ushort* __restrict__ mlo, int layer) {
    int node = blockIdx.x * 4 + (threadIdx.x >> 6);
    int lane = threadIdx.x & 63;
    int beg = ptr[node], end = ptr[node + 1];
    float a0 = 0.f, a1 = 0.f;
    int c = 0;
    for (int e = beg; e < end; e++) {
        int pk = packed[e];
        if ((pk >> 17) <= layer) {
            c++;
            size_t off = (size_t)(pk & 0x1FFFF) * D + lane * 2;
            uint vh = *reinterpret_cast<const uint*>(hhi + off);
            uint vl = *reinterpret_cast<const uint*>(hlo + off);
            a0 += bf2f(vh & 0xFFFFu) + bf2f(vl & 0xFFFFu);
            a1 += bf2f(vh >> 16) + bf2f(vl >> 16);
        }
    }
    float inv = 1.f / fmaxf((float)c, 1.f);
    a0 *= inv;
    a1 *= inv;
    uint h0, l0, h1, l1;
    splitf(a0, h0, l0);
    splitf(a1, h1, l1);
    size_t o = (size_t)node * D + lane * 2;
    *reinterpret_cast<uint*>(mhi + o) = h0 | (h1 << 16);
    *reinterpret_cast<uint*>(mlo + o) = l0 | (l1 << 16);
}

// ---- one (A,W) pair: 2x2 16x16 frags, K=128, 3-term split-bf16 (drops lo*lo)
__device__ __forceinline__ void gemm_pair(const ushort* __restrict__ Ahi,
                                          const ushort* __restrict__ Alo,
                                          const ushort* __restrict__ Whi,
                                          const ushort* __restrict__ Wlo,
                                          int ln15, int lg, f32x4 acc[2][2]) {
#pragma unroll 1
    for (int ks = 0; ks < 4; ks++) {
        int kof = ks * 32 + lg * 8;
        bf16x8 ah0 = *reinterpret_cast<const bf16x8*>(Ahi + (size_t)ln15 * D + kof);
        bf16x8 ah1 = *reinterpret_cast<const bf16x8*>(Ahi + (size_t)(16 + ln15) * D + kof);
        bf16x8 al0 = *reinterpret_cast<const bf16x8*>(Alo + (size_t)ln15 * D + kof);
        bf16x8 al1 = *reinterpret_cast<const bf16x8*>(Alo + (size_t)(16 + ln15) * D + kof);
        bf16x8 bh0 = *reinterpret_cast<const bf16x8*>(Whi + (size_t)ln15 * D + kof);
        bf16x8 bh1 = *reinterpret_cast<const bf16x8*>(Whi + (size_t)(16 + ln15) * D + kof);
        bf16x8 bl0 = *reinterpret_cast<const bf16x8*>(Wlo + (size_t)ln15 * D + kof);
        bf16x8 bl1 = *reinterpret_cast<const bf16x8*>(Wlo + (size_t)(16 + ln15) * D + kof);
        acc[0][0] = MFMA_BF16(ah0, bh0, acc[0][0]);
        acc[0][1] = MFMA_BF16(ah0, bh1, acc[0][1]);
        acc[1][0] = MFMA_BF16(ah1, bh0, acc[1][0]);
        acc[1][1] = MFMA_BF16(ah1, bh1, acc[1][1]);
        acc[0][0] = MFMA_BF16(ah0, bl0, acc[0][0]);
        acc[0][1] = MFMA_BF16(ah0, bl1, acc[0][1]);
        acc[1][0] = MFMA_BF16(ah1, bl0, acc[1][0]);
        acc[1][1] = MFMA_BF16(ah1, bl1, acc[1][1]);
        acc[0][0] = MFMA_BF16(al0, bh0, acc[0][0]);
        acc[0][1] = MFMA_BF16(al0, bh1, acc[0][1]);
        acc[1][0] = MFMA_BF16(al1, bh0, acc[1][0]);
        acc[1][1] = MFMA_BF16(al1, bh1, acc[1][1]);
    }
}

// ---- fused GEMM: out[n,:] = relu_mask( sum_p A_p[n,:] @ W_p^T + bias )
// block = 256 (4 waves); tile 32 rows x 128 cols; wave -> 32 cols
__global__ __launch_bounds__(256) void gemm_mfma(
    const ushort* __restrict__ mhi, const ushort* __restrict__ mlo,
    const ushort* __restrict__ hhi, const ushort* __restrict__ hlo,
    const ushort* __restrict__ Whi, const ushort* __restrict__ Wlo,
    const float* __restrict__ bias, const int* __restrict__ node_mask,
    int layer, float* __restrict__ out_f32, ushort* __restrict__ ohi,
    ushort* __restrict__ olo) {
    int tid = threadIdx.x;
    int wid = tid >> 6;
    int lane = tid & 63;
    int row0 = blockIdx.x * 32;
    int colbase = wid * 32;
    int ln15 = lane & 15;
    int lg = lane >> 4;
    size_t ro = (size_t)row0 * D;
    size_t wo = (size_t)colbase * D;

    f32x4 acc[2][2] = {};

#pragma unroll 1
    for (int p = 0; p < 3; p++) {
        gemm_pair(mhi + (size_t)p * N_NODES * D + ro, mlo + (size_t)p * N_NODES * D + ro,
                  Whi + (size_t)p * 16384 + wo, Wlo + (size_t)p * 16384 + wo, ln15, lg, acc);
    }
    gemm_pair(hhi + ro, hlo + ro, Whi + (size_t)3 * 16384 + wo, Wlo + (size_t)3 * 16384 + wo,
              ln15, lg, acc);

    // all global A-reads (incl. hhi/hlo rows this block will overwrite) must
    // complete before any wave writes the epilogue: intra-block RAW/WAR fence.
    __syncthreads();

    // C[row][col]: row = row0 + r*16 + lg*4 + j, col = colbase + cc*16 + ln15
    if (out_f32) {
#pragma unroll
        for (int r = 0; r < 2; r++)
#pragma unroll
            for (int j = 0; j < 4; j++) {
                int row = row0 + r * 16 + lg * 4 + j;
                bool valid = node_mask[row] <= layer;
#pragma unroll
                for (int cc = 0; cc < 2; cc++) {
                    int col = colbase + cc * 16 + ln15;
                    float v = acc[r][cc][j] + bias[col];
                    out_f32[(size_t)row * D + col] = valid ? fmaxf(v, 0.f) : 0.f;
                }
            }
    } else {
#pragma unroll
        for (int r = 0; r < 2; r++)
#pragma unroll
            for (int j = 0; j < 4; j++) {
                int row = row0 + r * 16 + lg * 4 + j;
                bool valid = node_mask[row] <= layer;
#pragma unroll
                for (int cc = 0; cc < 2; cc++) {
                    int col = colbase + cc * 16 + ln15;
                    float v = acc[r][cc][j] + bias[col];
                    v = valid ? fmaxf(v, 0.f) : 0.f;
                    uint hi, lo;
                    splitf(v, hi, lo);
                    ohi[(size_t)row * D + col] = (ushort)hi;
                    olo[(size_t)row * D + col] = (ushort)lo;
                }
            }
    }
}

extern "C" void kernel_launch(void* const* d_in, const int* in_sizes, int n_in,
                              void* d_out, int out_size, void* d_ws, size_t ws_size,
                              hipStream_t stream) {
    const float* x = (const float*)d_in[0];
    const int* eis[3] = {(const int*)d_in[1], (const int*)d_in[2], (const int*)d_in[3]};
    const int* node_mask = (const int*)d_in[4];
    const int* ems[3] = {(const int*)d_in[5], (const int*)d_in[6], (const int*)d_in[7]};
    const float* W_l = (const float*)d_in[8];
    const float* b_l = (const float*)d_in[9];
    const float* W_r = (const float*)d_in[10];

    // workspace: byte-identical footprint to the proven R1 layout
    ushort* hhi = (ushort*)d_ws;                               // N*D (25.6 MB)
    ushort* hlo = hhi + (size_t)N_NODES * D;                   // N*D
    ushort* mhi = hlo + (size_t)N_NODES * D;                   // 3*N*D (76.8 MB)
    ushort* mlo = mhi + (size_t)3 * N_NODES * D;               // 3*N*D
    int* cnt = (int*)(mlo + (size_t)3 * N_NODES * D);          // 3*N
    int* ptr = cnt + 3 * N_NODES;                              // 3*(N+1)
    int* fill = ptr + 3 * (N_NODES + 1);                       // 3*N
    int* packed = fill + 3 * N_NODES;                          // 3*E
    // whi/wlo/bsum live in cnt's slot (cnt is dead after scan_kernel): 788 KB <= 1.2 MB
    ushort* whi = (ushort*)cnt;                                // 3*4*16384 ushorts
    ushort* wlo = whi + 3 * 4 * 16384;                         // 3*4*16384 ushorts
    float* bsum = (float*)(wlo + 3 * 4 * 16384);               // 3*128 floats

    hipMemsetAsync(cnt, 0, (size_t)(3 * N_NODES + 3 * (N_NODES + 1) + 3 * N_NODES) * sizeof(int), stream);

    conv_x<<<N_NODES * D / 4 / 256, 256, 0, stream>>>(x, hhi, hlo);

    for (int t = 0; t < 3; t++)
        count_kernel<<<(N_EDGES + 255) / 256, 256, 0, stream>>>(eis[t], cnt + t * N_NODES);
    scan_kernel<<<3, 1024, 0, stream>>>(cnt, ptr);
    // cnt dead now; prep_w overwrites it with split weights
    prep_w<<<(3 * 4 * 16384 + 255) / 256, 256, 0, stream>>>(W_l, W_r, b_l, whi, wlo, bsum);
    for (int t = 0; t < 3; t++)
        fill_kernel<<<(N_EDGES + 255) / 256, 256, 0, stream>>>(
            eis[t], ems[t], ptr + t * (N_NODES + 1), fill + t * N_NODES, packed + (size_t)t * N_EDGES);

    for (int i = 0; i < 3; i++) {
        int layer = 3 - i;
        for (int t = 0; t < 3; t++)
            agg_kernel<<<N_NODES / 4, 256, 0, stream>>>(
                hhi, hlo, ptr + t * (N_NODES + 1), packed + (size_t)t * N_EDGES,
                mhi + (size_t)t * N_NODES * D, mlo + (size_t)t * N_NODES * D, layer);
        float* of = (i == 2) ? (float*)d_out : nullptr;
        gemm_mfma<<<N_NODES / 32, 256, 0, stream>>>(
            mhi, mlo, hhi, hlo,
            whi + (size_t)i * 4 * 16384, wlo + (size_t)i * 4 * 16384,
            bsum + (size_t)i * 128, node_mask, layer, of, hhi, hlo);
    }
}

// Round 5
// 1597.633 us; speedup vs baseline: 47.1404x; 1.1492x over previous
//
#include <hip/hip_runtime.h>

#define N_NODES 100000
#define N_EDGES 800000
#define D 128

typedef _Float16 f16x8 __attribute__((ext_vector_type(8)));
typedef _Float16 f16x4 __attribute__((ext_vector_type(4)));
typedef _Float16 f16x2 __attribute__((ext_vector_type(2)));
typedef float f32x4 __attribute__((ext_vector_type(4)));

#define MFMA_F16(a, b, c) __builtin_amdgcn_mfma_f32_16x16x32_f16((a), (b), (c), 0, 0, 0)

// ---- x f32 -> fp16 plane
__global__ void conv_x(const float* __restrict__ x, _Float16* __restrict__ h) {
    int idx = blockIdx.x * 256 + threadIdx.x;
    float4 v = reinterpret_cast<const float4*>(x)[idx];
    f16x4 o = {(_Float16)v.x, (_Float16)v.y, (_Float16)v.z, (_Float16)v.w};
    reinterpret_cast<f16x4*>(h)[idx] = o;
}

// ---- weight prep: w{hi,lo}[i][slot][o][k] fp16; slot 0..2 = W_l[i][t], slot 3 = sum_t W_r[i][t]
__global__ void prep_w(const float* __restrict__ W_l, const float* __restrict__ W_r,
                       const float* __restrict__ b_l, _Float16* __restrict__ whi,
                       _Float16* __restrict__ wlo, float* __restrict__ bsum) {
    int idx = blockIdx.x * 256 + threadIdx.x;
    if (idx < 3 * 4 * 16384) {
        int i = idx / (4 * 16384);
        int rem = idx % (4 * 16384);
        int slot = rem / 16384;
        int ok = rem % 16384;
        float v;
        if (slot < 3) {
            v = W_l[(size_t)(i * 3 + slot) * 16384 + ok];
        } else {
            const float* base = W_r + (size_t)i * 3 * 16384;
            v = base[ok] + base[16384 + ok] + base[2 * 16384 + ok];
        }
        _Float16 hi = (_Float16)v;
        whi[idx] = hi;
        wlo[idx] = (_Float16)(v - (float)hi);
    }
    if (idx < 3 * 128) {
        int i = idx / 128, o = idx % 128;
        const float* bb = b_l + (size_t)i * 3 * 128;
        bsum[idx] = bb[o] + bb[128 + o] + bb[256 + o];
    }
}

// ---- CSR build (per relation)
__global__ void count_kernel(const int* __restrict__ ei, int* __restrict__ cnt) {
    int e = blockIdx.x * 256 + threadIdx.x;
    if (e < N_EDGES) atomicAdd(&cnt[ei[N_EDGES + e]], 1);
}

__global__ void scan_kernel(const int* __restrict__ cnt, int* __restrict__ ptr) {
    int r = blockIdx.x;
    const int* c = cnt + (size_t)r * N_NODES;
    int* p = ptr + (size_t)r * (N_NODES + 1);
    __shared__ int sums[1024];
    int tid = threadIdx.x;
    const int CH = (N_NODES + 1023) / 1024;
    int base = tid * CH;
    int s = 0;
    for (int j = 0; j < CH; j++) {
        int idx = base + j;
        if (idx < N_NODES) s += c[idx];
    }
    sums[tid] = s;
    __syncthreads();
    for (int off = 1; off < 1024; off <<= 1) {
        int v = sums[tid];
        int add = (tid >= off) ? sums[tid - off] : 0;
        __syncthreads();
        sums[tid] = v + add;
        __syncthreads();
    }
    int run = (tid == 0) ? 0 : sums[tid - 1];
    for (int j = 0; j < CH; j++) {
        int idx = base + j;
        if (idx < N_NODES) {
            p[idx] = run;
            run += c[idx];
        }
    }
    if (tid == 1023) p[N_NODES] = sums[1023];
}

__global__ void fill_kernel(const int* __restrict__ ei, const int* __restrict__ em,
                            const int* __restrict__ ptr, int* __restrict__ fill,
                            int* __restrict__ packed) {
    int e = blockIdx.x * 256 + threadIdx.x;
    if (e < N_EDGES) {
        int dst = ei[N_EDGES + e];
        int src = ei[e];
        int m = em[e];
        int pos = ptr[dst] + atomicAdd(&fill[dst], 1);
        packed[pos] = src | (m << 17);
    }
}

// ---- fused layer: gather 3 relation-means into LDS, then MFMA GEMM (4 pairs, fp16)
// block = 256 thr (4 waves) = 32 dst rows x 128 cols; reads h_in, writes h_out/d_out.
__global__ __launch_bounds__(256, 4) void fused_layer(
    const _Float16* __restrict__ h_in, const int* __restrict__ ptr,
    const int* __restrict__ packed, const _Float16* __restrict__ Whi,
    const _Float16* __restrict__ Wlo, const float* __restrict__ bias,
    const int* __restrict__ node_mask, int layer,
    _Float16* __restrict__ h_out, float* __restrict__ out_f32) {
    __shared__ __align__(16) _Float16 smean[3][32][136];  // pad 136: 2-way banks = free
    int tid = threadIdx.x;
    int wid = tid >> 6;
    int lane = tid & 63;
    int row0 = blockIdx.x * 32;

    // ---- phase 1: gather means. 96 (relation,node) tasks, 24 per wave.
    for (int t = wid * 24; t < wid * 24 + 24; t++) {
        int r = t >> 5;
        int n = t & 31;
        int g = row0 + n;
        const int* pp = ptr + (size_t)r * (N_NODES + 1);
        const int* pk = packed + (size_t)r * N_EDGES;
        int beg = pp[g], end = pp[g + 1];
        float a0 = 0.f, a1 = 0.f;
        int c = 0;
#pragma unroll 4
        for (int e = beg; e < end; e++) {
            int p = pk[e];
            if ((p >> 17) <= layer) {
                c++;
                f16x2 hv = *reinterpret_cast<const f16x2*>(h_in + (size_t)(p & 0x1FFFF) * D + lane * 2);
                a0 += (float)hv.x;
                a1 += (float)hv.y;
            }
        }
        float inv = 1.f / fmaxf((float)c, 1.f);
        f16x2 mv = {(_Float16)(a0 * inv), (_Float16)(a1 * inv)};
        *reinterpret_cast<f16x2*>(&smean[r][n][lane * 2]) = mv;
    }
    __syncthreads();

    // ---- phase 2: GEMM. wave -> 32 cols; 2x2 16x16 frags; K=128; 2 terms (Whi,Wlo).
    int colbase = wid * 32;
    int ln15 = lane & 15;
    int lg = lane >> 4;
    f32x4 acc[2][2] = {};

#pragma unroll
    for (int p = 0; p < 4; p++) {
        const _Float16* Whp = Whi + (size_t)p * 16384 + (size_t)colbase * D;
        const _Float16* Wlp = Wlo + (size_t)p * 16384 + (size_t)colbase * D;
#pragma unroll
        for (int ks = 0; ks < 4; ks++) {
            int kof = ks * 32 + lg * 8;
            f16x8 a0f, a1f;
            if (p < 3) {
                a0f = *reinterpret_cast<const f16x8*>(&smean[p][ln15][kof]);
                a1f = *reinterpret_cast<const f16x8*>(&smean[p][16 + ln15][kof]);
            } else {
                a0f = *reinterpret_cast<const f16x8*>(h_in + (size_t)(row0 + ln15) * D + kof);
                a1f = *reinterpret_cast<const f16x8*>(h_in + (size_t)(row0 + 16 + ln15) * D + kof);
            }
            f16x8 bh0 = *reinterpret_cast<const f16x8*>(Whp + (size_t)ln15 * D + kof);
            f16x8 bh1 = *reinterpret_cast<const f16x8*>(Whp + (size_t)(16 + ln15) * D + kof);
            f16x8 bl0 = *reinterpret_cast<const f16x8*>(Wlp + (size_t)ln15 * D + kof);
            f16x8 bl1 = *reinterpret_cast<const f16x8*>(Wlp + (size_t)(16 + ln15) * D + kof);
            acc[0][0] = MFMA_F16(a0f, bh0, acc[0][0]);
            acc[0][1] = MFMA_F16(a0f, bh1, acc[0][1]);
            acc[1][0] = MFMA_F16(a1f, bh0, acc[1][0]);
            acc[1][1] = MFMA_F16(a1f, bh1, acc[1][1]);
            acc[0][0] = MFMA_F16(a0f, bl0, acc[0][0]);
            acc[0][1] = MFMA_F16(a0f, bl1, acc[0][1]);
            acc[1][0] = MFMA_F16(a1f, bl0, acc[1][0]);
            acc[1][1] = MFMA_F16(a1f, bl1, acc[1][1]);
        }
    }

    // ---- epilogue: C row = row0 + r*16 + lg*4 + j, col = colbase + cc*16 + ln15.
    // Writes go to h_out (!= h_in) or d_out: no intra-kernel hazard.
#pragma unroll
    for (int r = 0; r < 2; r++)
#pragma unroll
        for (int j = 0; j < 4; j++) {
            int row = row0 + r * 16 + lg * 4 + j;
            bool valid = node_mask[row] <= layer;
#pragma unroll
            for (int cc = 0; cc < 2; cc++) {
                int col = colbase + cc * 16 + ln15;
                float v = acc[r][cc][j] + bias[col];
                v = valid ? fmaxf(v, 0.f) : 0.f;
                if (out_f32)
                    out_f32[(size_t)row * D + col] = v;
                else
                    h_out[(size_t)row * D + col] = (_Float16)v;
            }
        }
}

extern "C" void kernel_launch(void* const* d_in, const int* in_sizes, int n_in,
                              void* d_out, int out_size, void* d_ws, size_t ws_size,
                              hipStream_t stream) {
    const float* x = (const float*)d_in[0];
    const int* eis[3] = {(const int*)d_in[1], (const int*)d_in[2], (const int*)d_in[3]};
    const int* node_mask = (const int*)d_in[4];
    const int* ems[3] = {(const int*)d_in[5], (const int*)d_in[6], (const int*)d_in[7]};
    const float* W_l = (const float*)d_in[8];
    const float* b_l = (const float*)d_in[9];
    const float* W_r = (const float*)d_in[10];

    // workspace (~66 MB)
    _Float16* hA = (_Float16*)d_ws;                            // N*D
    _Float16* hB = hA + (size_t)N_NODES * D;                   // N*D
    _Float16* whi = hB + (size_t)N_NODES * D;                  // 3*4*16384
    _Float16* wlo = whi + 3 * 4 * 16384;                       // 3*4*16384
    float* bsum = (float*)(wlo + 3 * 4 * 16384);               // 3*128
    int* cnt = (int*)(bsum + 3 * 128);                         // 3*N
    int* ptr = cnt + 3 * N_NODES;                              // 3*(N+1)
    int* fill = ptr + 3 * (N_NODES + 1);                       // 3*N
    int* packed = fill + 3 * N_NODES;                          // 3*E

    hipMemsetAsync(cnt, 0, (size_t)(3 * N_NODES + 3 * (N_NODES + 1) + 3 * N_NODES) * sizeof(int), stream);

    conv_x<<<N_NODES * D / 4 / 256, 256, 0, stream>>>(x, hA);
    prep_w<<<(3 * 4 * 16384 + 255) / 256, 256, 0, stream>>>(W_l, W_r, b_l, whi, wlo, bsum);

    for (int t = 0; t < 3; t++)
        count_kernel<<<(N_EDGES + 255) / 256, 256, 0, stream>>>(eis[t], cnt + t * N_NODES);
    scan_kernel<<<3, 1024, 0, stream>>>(cnt, ptr);
    for (int t = 0; t < 3; t++)
        fill_kernel<<<(N_EDGES + 255) / 256, 256, 0, stream>>>(
            eis[t], ems[t], ptr + t * (N_NODES + 1), fill + t * N_NODES, packed + (size_t)t * N_EDGES);

    _Float16* hin = hA;
    _Float16* hout = hB;
    for (int i = 0; i < 3; i++) {
        int layer = 3 - i;
        float* of = (i == 2) ? (float*)d_out : nullptr;
        fused_layer<<<N_NODES / 32, 256, 0, stream>>>(
            hin, ptr, packed, whi + (size_t)i * 4 * 16384, wlo + (size_t)i * 4 * 16384,
            bsum + (size_t)i * 128, node_mask, layer, hout, of);
        _Float16* tmp = hin; hin = hout; hout = tmp;
    }
}